// Round 14
// baseline (830.654 us; speedup 1.0000x reference)
//
#include <hip/hip_runtime.h>
#include <hip/hip_bf16.h>

__device__ __forceinline__ float lrelu(float x){ return x > 0.f ? x : 0.01f*x; }
__device__ __forceinline__ float eluf(float x){ return x > 0.f ? x : __expf(x) - 1.f; }

// bf16 pack/unpack (RNE)
__device__ __forceinline__ unsigned packbf2(float a, float b){
  unsigned ua = __float_as_uint(a); ua += 0x7FFF + ((ua >> 16) & 1);
  unsigned ub = __float_as_uint(b); ub += 0x7FFF + ((ub >> 16) & 1);
  return (ua >> 16) | (ub & 0xFFFF0000u);
}
__device__ __forceinline__ float bflo(unsigned u){ return __uint_as_float(u << 16); }
__device__ __forceinline__ float bfhi(unsigned u){ return __uint_as_float(u & 0xFFFF0000u); }

// ---------- edge_index dtype normalize ----------
__global__ void detect_idx(const int* __restrict__ p, int words, int* __restrict__ flag){
  __shared__ int any;
  if (threadIdx.x == 0) any = 0;
  __syncthreads();
  int v = 0;
  for (int i = threadIdx.x; i < words/2; i += blockDim.x) v |= p[2*i + 1];
  if (v) atomicOr(&any, 1);
  __syncthreads();
  if (threadIdx.x == 0) *flag = (any == 0) ? 1 : 0;
}

__global__ void convert_idx(const void* __restrict__ src, int n, const int* __restrict__ flag,
                            int* __restrict__ out){
  int i = blockIdx.x*256 + threadIdx.x;
  if (i >= n) return;
  out[i] = (*flag) ? (int)((const long long*)src)[i] : ((const int*)src)[i];
}

// ---------- CSR ----------
__global__ void hist_k(const int* __restrict__ dst, int E, int* __restrict__ deg){
  int e = blockIdx.x*256 + threadIdx.x;
  if (e < E) atomicAdd(&deg[dst[e]], 1);
}

__launch_bounds__(1024)
__global__ void scan_k(const int* __restrict__ deg, int N,
                       int* __restrict__ rp, int* __restrict__ cursor){
  __shared__ int part[1024];
  int tid = threadIdx.x;
  int chunk = (N + 1023) / 1024;
  int lo = tid*chunk, hi = min(lo + chunk, N);
  int s = 0;
  for (int i = lo; i < hi; i++) s += deg[i];
  part[tid] = s;
  __syncthreads();
  // Hillis-Steele inclusive scan over the 1024 partials
  for (int off = 1; off < 1024; off <<= 1){
    int t = (tid >= off) ? part[tid - off] : 0;
    __syncthreads();
    part[tid] += t;
    __syncthreads();
  }
  int run = part[tid] - s;          // exclusive prefix of this chunk
  if (tid == 1023) rp[N] = part[1023];
  for (int i = lo; i < hi; i++){
    rp[i] = run; cursor[i] = run;
    run += deg[i];
  }
}

// scatter: colsrc[p]=src[e], col[p]=e, dstc[p]=dst[e]
__global__ void scatter_k(const int* __restrict__ srcA, const int* __restrict__ dstA, int E,
                          int* __restrict__ cursor, int* __restrict__ colsrc,
                          int* __restrict__ col, int* __restrict__ dstc){
  int e = blockIdx.x*256 + threadIdx.x;
  if (e < E){
    int d = dstA[e];
    int p = atomicAdd(&cursor[d], 1);
    colsrc[p] = srcA[e];
    col[p] = e;
    dstc[p] = d;
  }
}

// ---------- folded weights (R: k-major, as staged into LDS by aggfin) ----------
__global__ void prep_k(const float* __restrict__ We, const float* __restrict__ a,
                       const float* __restrict__ Wen, const float* __restrict__ Weu,
                       int doU, float* __restrict__ Qt, float* __restrict__ R,
                       float* __restrict__ U){
  int idx = blockIdx.x*256 + threadIdx.x;
  if (idx < 256){
    int h = idx >> 6, k = idx & 63;
    float s = 0.f;
    for (int c = 0; c < 32; c++) s += We[k*128 + h*32 + c] * a[64 + c];
    Qt[h*64 + k] = s;
  } else if (idx < 256 + 8192){
    int t = idx - 256;
    int k = t >> 7, j = t & 127;      // j = h*32+d
    int h = j >> 5, d = j & 31;
    float s = 0.f;
    for (int c = 0; c < 32; c++) s += We[k*128 + h*32 + c] * Wen[(32 + c)*32 + d];
    R[k*128 + j] = s;
  } else if (doU && idx < 256 + 8192 + 2048){
    int t = idx - 256 - 8192;
    int k = t >> 5, d = t & 31;
    float s = 0.f;
    for (int c = 0; c < 32; c++){
      float mb = 0.25f*(We[k*128 + c] + We[k*128 + 32 + c] + We[k*128 + 64 + c] + We[k*128 + 96 + c]);
      s += mb * Weu[(64 + c)*32 + d];
    }
    U[k*32 + d] = s;
  }
}

// ---------- fused node-side: xp (LDS only) -> scores + xw(bf16 packed) ----------
template<int IN>
__launch_bounds__(256, 2)
__global__ void node_prep(const float* __restrict__ x, const float* __restrict__ Wn,
                          const float* __restrict__ a, const float* __restrict__ Wen,
                          int N, float* __restrict__ sdst, float* __restrict__ ssrc,
                          unsigned* __restrict__ xwb){
  __shared__ float sXpT[128][68];   // xp transposed [j][n]
  __shared__ float sX[32][68];      // x chunk transposed [k][n]
  __shared__ float sW[32][132];     // Wn chunk [k][j]
  __shared__ float sWen[32][36];    // Wen [c][d]
  __shared__ float sa[96];
  int tid = threadIdx.x;
  int nbase = blockIdx.x*64;

  if (tid < 96) sa[tid] = a[tid];
  {
    int c = tid >> 3, d4 = tid & 7;
    float4 v = *(const float4*)(Wen + c*32 + d4*4);
    *(float4*)&sWen[c][d4*4] = v;
  }

  int nq = tid >> 4, jq = tid & 15;   // thread = 4n x 8j
  float acc[8][4];
  #pragma unroll
  for (int ji = 0; ji < 8; ji++)
    #pragma unroll
    for (int ni = 0; ni < 4; ni++) acc[ji][ni] = 0.f;

  for (int kc = 0; kc < IN/32; kc++){
    __syncthreads();
    #pragma unroll
    for (int i = 0; i < 2; i++){
      int q = tid + i*256;
      int n = q >> 3, kq = q & 7;
      int nn = min(nbase + n, N - 1);
      float4 v = *(const float4*)(x + (size_t)nn*IN + kc*32 + kq*4);
      sX[kq*4 + 0][n] = v.x;
      sX[kq*4 + 1][n] = v.y;
      sX[kq*4 + 2][n] = v.z;
      sX[kq*4 + 3][n] = v.w;
    }
    #pragma unroll
    for (int i = 0; i < 4; i++){
      int q = tid + i*256;
      int kk = q >> 5, j4 = q & 31;
      float4 v = *(const float4*)(Wn + (size_t)(kc*32 + kk)*128 + j4*4);
      *(float4*)&sW[kk][j4*4] = v;
    }
    __syncthreads();
    #pragma unroll 8
    for (int k = 0; k < 32; k++){
      float4 xr = *(const float4*)&sX[k][nq*4];
      float4 w0 = *(const float4*)&sW[k][jq*8];
      float4 w1 = *(const float4*)&sW[k][jq*8 + 4];
      float xn[4] = {xr.x, xr.y, xr.z, xr.w};
      float wj[8] = {w0.x, w0.y, w0.z, w0.w, w1.x, w1.y, w1.z, w1.w};
      #pragma unroll
      for (int ji = 0; ji < 8; ji++)
        #pragma unroll
        for (int ni = 0; ni < 4; ni++)
          acc[ji][ni] += xn[ni] * wj[ji];
    }
  }
  #pragma unroll
  for (int ji = 0; ji < 8; ji++){
    float4 v = make_float4(acc[ji][0], acc[ji][1], acc[ji][2], acc[ji][3]);
    *(float4*)&sXpT[jq*8 + ji][nq*4] = v;
  }
  __syncthreads();

  // scores
  {
    int n = tid >> 2, h = tid & 3;
    float s1 = 0.f, s2 = 0.f;
    #pragma unroll
    for (int cc = 0; cc < 32; cc++){
      int c = (cc + tid) & 31;
      float v = sXpT[h*32 + c][n];
      s1 += v * sa[c];
      s2 += v * sa[32 + c];
    }
    int gn = nbase + n;
    if (gn < N){ sdst[gn*4 + h] = s1; ssrc[gn*4 + h] = s2; }
  }

  // xw packed bf16
  {
    int nd2 = tid >> 3, dq = tid & 7;
    int n0 = nd2*2, d0 = dq*4;
    float acc2[2][4][4];
    #pragma unroll
    for (int ni = 0; ni < 2; ni++)
      #pragma unroll
      for (int di = 0; di < 4; di++)
        #pragma unroll
        for (int h = 0; h < 4; h++) acc2[ni][di][h] = 0.f;
    #pragma unroll 4
    for (int c = 0; c < 32; c++){
      float4 wv = *(const float4*)&sWen[c][d0];
      float wvA[4] = {wv.x, wv.y, wv.z, wv.w};
      #pragma unroll
      for (int h = 0; h < 4; h++){
        float2 xv = *(const float2*)&sXpT[h*32 + c][n0];
        float xvA[2] = {xv.x, xv.y};
        #pragma unroll
        for (int ni = 0; ni < 2; ni++)
          #pragma unroll
          for (int di = 0; di < 4; di++)
            acc2[ni][di][h] += xvA[ni] * wvA[di];
      }
    }
    #pragma unroll
    for (int ni = 0; ni < 2; ni++){
      int gn = nbase + n0 + ni;
      if (gn < N){
        uint4 A, B;
        A.x = packbf2(acc2[ni][0][0], acc2[ni][0][1]);
        A.y = packbf2(acc2[ni][1][0], acc2[ni][1][1]);
        A.z = packbf2(acc2[ni][2][0], acc2[ni][2][1]);
        A.w = packbf2(acc2[ni][3][0], acc2[ni][3][1]);
        B.x = packbf2(acc2[ni][0][2], acc2[ni][0][3]);
        B.y = packbf2(acc2[ni][1][2], acc2[ni][1][3]);
        B.z = packbf2(acc2[ni][2][2], acc2[ni][2][3]);
        B.w = packbf2(acc2[ni][3][2], acc2[ni][3][3]);
        *(uint4*)(xwb + (size_t)gn*64 + d0) = A;
        *(uint4*)(xwb + (size_t)gn*64 + 32 + d0) = B;
      }
    }
  }
}

// ---------- edge pass, CSR-order GATHER (1 slot/thread): random full-line ea reads,
// all writes sequential. min-waves hint: VGPR 56 <= 64 cap, so codegen unchanged. ----------
__launch_bounds__(256, 8)
__global__ void se12_k(const float* __restrict__ ea, const float* __restrict__ Qt1,
                       const float* __restrict__ Qt2, const int* __restrict__ col,
                       int E, float* __restrict__ se1c, float* __restrict__ se2c,
                       unsigned* __restrict__ eac){
  int p = blockIdx.x*256 + threadIdx.x;
  if (p >= E) return;
  int e = col[p];
  float x[64];
  {
    const float4* q = (const float4*)(ea + (size_t)e*64);
    #pragma unroll
    for (int t = 0; t < 16; t++){
      float4 v = q[t];
      x[4*t] = v.x; x[4*t+1] = v.y; x[4*t+2] = v.z; x[4*t+3] = v.w;
    }
  }
  float acc[8] = {0,0,0,0,0,0,0,0};
  #pragma unroll
  for (int t = 0; t < 16; t++){
    #pragma unroll
    for (int j = 0; j < 4; j++){
      const float* q1 = Qt1 + j*64 + 4*t;
      const float* q2 = Qt2 + j*64 + 4*t;
      acc[j]     += x[4*t]*q1[0] + x[4*t+1]*q1[1] + x[4*t+2]*q1[2] + x[4*t+3]*q1[3];
      acc[4 + j] += x[4*t]*q2[0] + x[4*t+1]*q2[1] + x[4*t+2]*q2[2] + x[4*t+3]*q2[3];
    }
  }
  *(float4*)(se1c + (size_t)p*4) = make_float4(acc[0], acc[1], acc[2], acc[3]);
  *(float4*)(se2c + (size_t)p*4) = make_float4(acc[4], acc[5], acc[6], acc[7]);
  unsigned* dst = eac + (size_t)p*32;
  #pragma unroll
  for (int t = 0; t < 8; t++){
    uint4 wv;
    wv.x = packbf2(x[4*t    ], x[32 + 4*t    ]);
    wv.y = packbf2(x[4*t + 1], x[32 + 4*t + 1]);
    wv.z = packbf2(x[4*t + 2], x[32 + 4*t + 2]);
    wv.w = packbf2(x[4*t + 3], x[32 + 4*t + 3]);
    ((uint4*)dst)[t] = wv;
  }
}

// ---------- fused aggregate + finalize: 512 threads = 8 waves = 8 nodes/block. ----------
template<int MODE>   // 0: outF = elu(emb);  1: outF = emb raw, outElu = elu(emb)
__global__ void __launch_bounds__(512)
aggfin_k(const int* __restrict__ rp, const int* __restrict__ colsrc,
         const float* __restrict__ sdst, const float* __restrict__ ssrc,
         const float* __restrict__ sec, const unsigned* __restrict__ xwb,
         const unsigned* __restrict__ eac, const float* __restrict__ R,
         int N, float* __restrict__ outF, float* __restrict__ outElu){
  __shared__ float sR[8192];
  __shared__ float sG[8][4][64];
  {
    const float4* r4 = (const float4*)R;
    float4* s4 = (float4*)sR;
    s4[threadIdx.x]       = r4[threadIdx.x];
    s4[threadIdx.x + 512] = r4[threadIdx.x + 512];
    s4[threadIdx.x + 1024] = r4[threadIdx.x + 1024];
    s4[threadIdx.x + 1536] = r4[threadIdx.x + 1536];
  }
  __syncthreads();

  int nb   = threadIdx.x >> 6;     // wave id = node slot (0..7)
  int lane = threadIdx.x & 63;
  int half = lane >> 5;
  int c    = lane & 31;
  int nid  = blockIdx.x*8 + nb;
  bool act = nid < N;
  int n = act ? nid : N - 1;
  float4 sdv = *(const float4*)(sdst + (size_t)n*4);
  float4 snv = *(const float4*)(ssrc + (size_t)n*4);
  float sd[4] = {sdv.x, sdv.y, sdv.z, sdv.w};
  float dn[4], ax[4], g0[4], g1[4];
  {
    float sn[4] = {snv.x, snv.y, snv.z, snv.w};
    unsigned wA = xwb[(size_t)n*64 + c], wB = xwb[(size_t)n*64 + 32 + c];
    float xwh[4] = {bflo(wA), bfhi(wA), bflo(wB), bfhi(wB)};
    #pragma unroll
    for (int h = 0; h < 4; h++){
      if (half == 0){                                    // self loop (ep = 0)
        float ex = __expf(lrelu(sd[h] + sn[h]));
        dn[h] = ex;
        ax[h] = ex * xwh[h];
      } else { dn[h] = 0.f; ax[h] = 0.f; }
      g0[h] = 0.f; g1[h] = 0.f;
    }
  }
  int beg = rp[n], end = rp[n+1];
  #pragma unroll 2
  for (int i = beg + half; i < end; i += 2){
    int s = colsrc[i];
    float4 sv = *(const float4*)(sec + (size_t)i*4);
    float4 sr = *(const float4*)(ssrc + (size_t)s*4);
    unsigned ep = eac[(size_t)i*32 + c];
    unsigned wA = xwb[(size_t)s*64 + c];
    unsigned wB = xwb[(size_t)s*64 + 32 + c];
    float e0 = bflo(ep), e1 = bfhi(ep);
    float ex0 = __expf(lrelu(sd[0] + sr.x + sv.x));
    float ex1 = __expf(lrelu(sd[1] + sr.y + sv.y));
    float ex2 = __expf(lrelu(sd[2] + sr.z + sv.z));
    float ex3 = __expf(lrelu(sd[3] + sr.w + sv.w));
    dn[0] += ex0; dn[1] += ex1; dn[2] += ex2; dn[3] += ex3;
    ax[0] += ex0*bflo(wA); ax[1] += ex1*bfhi(wA);
    ax[2] += ex2*bflo(wB); ax[3] += ex3*bfhi(wB);
    g0[0] += ex0*e0; g0[1] += ex1*e0; g0[2] += ex2*e0; g0[3] += ex3*e0;
    g1[0] += ex0*e1; g1[1] += ex1*e1; g1[2] += ex2*e1; g1[3] += ex3*e1;
  }
  #pragma unroll
  for (int h = 0; h < 4; h++){
    dn[h] += __shfl_xor(dn[h], 32);
    ax[h] += __shfl_xor(ax[h], 32);
    g0[h] += __shfl_xor(g0[h], 32);
    g1[h] += __shfl_xor(g1[h], 32);
  }
  if (half == 0){
    #pragma unroll
    for (int h = 0; h < 4; h++){
      sG[nb][h][c]      = g0[h];
      sG[nb][h][32 + c] = g1[h];
    }
  }
  // no __syncthreads: sG[nb] written+read by the SAME wave (lgkmcnt orders it)
  float val = 0.f;
  #pragma unroll
  for (int hh = 0; hh < 2; hh++){
    int h = half*2 + hh;
    float s = ax[h];
    const float* g = &sG[nb][h][0];
    #pragma unroll 16
    for (int k = 0; k < 64; k++) s += g[k] * sR[k*128 + h*32 + c];
    val += s / (dn[h] + 1e-16f);
  }
  val += __shfl_xor(val, 32);
  val *= 0.25f;
  if (act && half == 0){
    if (MODE == 0){
      outF[(size_t)n*32 + c] = eluf(val);
    } else {
      outF[(size_t)n*32 + c] = val;
      outElu[(size_t)n*32 + c] = eluf(val);
    }
  }
}

// ---------- edge update (layer 2) ----------
__launch_bounds__(256)
__global__ void node_u(const float* __restrict__ nemb, const float* __restrict__ Weu,
                       int N, float* __restrict__ nu1, float* __restrict__ nu2){
  __shared__ float w1[1024], w2[1024];
  for (int i = threadIdx.x; i < 1024; i += 256){ w1[i] = Weu[i]; w2[i] = Weu[1024 + i]; }
  __syncthreads();
  int idx = blockIdx.x*256 + threadIdx.x;
  if (idx >= N*32) return;
  int n = idx >> 5, d = idx & 31;
  float s1 = 0.f, s2 = 0.f;
  #pragma unroll
  for (int c = 0; c < 32; c++){
    float v = nemb[n*32 + c];
    s1 += v * w1[c*32 + d];
    s2 += v * w2[c*32 + d];
  }
  nu1[idx] = s1;
  nu2[idx] = s2;
}

// ---------- edge output, CSR-order: lane = CSR slot p; reads eac[p] (bf16, sequential),
// nu gathers; writes out[col[p]] — full 128B-line scatter (no amplification). ----------
__launch_bounds__(256)
__global__ void edge_out(const int* __restrict__ col, const int* __restrict__ colsrc,
                         const int* __restrict__ dstc,
                         const float* __restrict__ nu1, const float* __restrict__ nu2,
                         const unsigned* __restrict__ eac, const float* __restrict__ U,
                         int E, float* __restrict__ out){
  int p = blockIdx.x*256 + threadIdx.x;
  if (p >= E) return;
  int e = col[p], s = colsrc[p], d = dstc[p];
  unsigned w[32];
  {
    const uint4* q = (const uint4*)(eac + (size_t)p*32);
    #pragma unroll
    for (int t = 0; t < 8; t++){
      uint4 v = q[t];
      w[4*t] = v.x; w[4*t+1] = v.y; w[4*t+2] = v.z; w[4*t+3] = v.w;
    }
  }
  float acc[32];
  {
    const float4* a4 = (const float4*)(nu1 + (size_t)s*32);
    const float4* b4 = (const float4*)(nu2 + (size_t)d*32);
    #pragma unroll
    for (int t = 0; t < 8; t++){
      float4 av = a4[t], bv = b4[t];
      acc[4*t]     = av.x + bv.x;
      acc[4*t + 1] = av.y + bv.y;
      acc[4*t + 2] = av.z + bv.z;
      acc[4*t + 3] = av.w + bv.w;
    }
  }
  #pragma unroll 4
  for (int t = 0; t < 32; t++){
    float lo = bflo(w[t]);          // ea[t]
    float hi = bfhi(w[t]);          // ea[32+t]
    const float* u0 = U + (size_t)t*32;
    const float* u1 = U + (size_t)(32 + t)*32;
    #pragma unroll
    for (int j = 0; j < 32; j++)
      acc[j] += lo*u0[j] + hi*u1[j];
  }
  float4* o4 = (float4*)(out + (size_t)e*32);
  #pragma unroll
  for (int t = 0; t < 8; t++)
    o4[t] = make_float4(fmaxf(acc[4*t], 0.f), fmaxf(acc[4*t + 1], 0.f),
                        fmaxf(acc[4*t + 2], 0.f), fmaxf(acc[4*t + 3], 0.f));
}

extern "C" void kernel_launch(void* const* d_in, const int* in_sizes, int n_in,
                              void* d_out, int out_size, void* d_ws, size_t ws_size,
                              hipStream_t stream){
  const float* x    = (const float*)d_in[0];
  const float* ea   = (const float*)d_in[1];
  const void*  eidx = d_in[2];
  const float* Wn1  = (const float*)d_in[3];
  const float* We1  = (const float*)d_in[4];
  const float* a1   = (const float*)d_in[5];
  const float* Wen1 = (const float*)d_in[6];
  const float* Weu1 = (const float*)d_in[7];  (void)Weu1;
  const float* Wn2  = (const float*)d_in[8];
  const float* We2  = (const float*)d_in[9];
  const float* a2   = (const float*)d_in[10];
  const float* Wen2 = (const float*)d_in[11];
  const float* Weu2 = (const float*)d_in[12];
  const int N = in_sizes[0] / 128;
  const int E = in_sizes[1] / 64;

  char* w = (char*)d_ws;
  size_t off = 0;
  auto alloc = [&](size_t bytes) -> char* {
    char* p = w + off;
    off = (off + bytes + 255) & ~(size_t)255;
    return p;
  };
  int*      flag   = (int*)     alloc(256);
  int*      idx32  = (int*)     alloc((size_t)2*E*4);
  int*      deg    = (int*)     alloc((size_t)N*4);
  int*      cursor = (int*)     alloc((size_t)N*4);
  int*      rp     = (int*)     alloc(((size_t)N + 1)*4);
  int*      colsrc = (int*)     alloc((size_t)E*4);
  int*      col    = (int*)     alloc((size_t)E*4);
  int*      dstc   = (int*)     alloc((size_t)E*4);
  float*    sdst   = (float*)   alloc((size_t)N*4*4);
  float*    ssrc   = (float*)   alloc((size_t)N*4*4);
  unsigned* xwb    = (unsigned*)alloc((size_t)N*64*4);
  float*    se1c   = (float*)   alloc((size_t)E*4*4);
  float*    se2c   = (float*)   alloc((size_t)E*4*4);
  unsigned* eac    = (unsigned*)alloc((size_t)E*32*4);
  float*    x1     = (float*)   alloc((size_t)N*32*4);
  float*    nemb2  = (float*)   alloc((size_t)N*32*4);
  float*    nu1    = (float*)   alloc((size_t)N*32*4);
  float*    nu2    = (float*)   alloc((size_t)N*32*4);
  float*    Qt1    = (float*)   alloc(4*64*4);
  float*    Qt2    = (float*)   alloc(4*64*4);
  float*    R1     = (float*)   alloc(64*128*4);
  float*    R2     = (float*)   alloc(64*128*4);
  float*    U      = (float*)   alloc(64*32*4);

  float* outN = (float*)d_out;
  float* outE = outN + (size_t)N*32;

  const int* srcA = idx32;
  const int* dstA = idx32 + E;

  // graph normalize + CSR over dst
  detect_idx<<<1, 1024, 0, stream>>>((const int*)eidx, (2*E < 8192) ? 2*E : 8192, flag);
  convert_idx<<<(2*E + 255)/256, 256, 0, stream>>>(eidx, 2*E, flag, idx32);
  hipMemsetAsync(deg, 0, (size_t)N*4, stream);
  hist_k<<<(E + 255)/256, 256, 0, stream>>>(dstA, E, deg);
  scan_k<<<1, 1024, 0, stream>>>(deg, N, rp, cursor);
  scatter_k<<<(E + 255)/256, 256, 0, stream>>>(srcA, dstA, E, cursor, colsrc, col, dstc);

  // folded weights + edge pass (CSR-order gather; sequential writes)
  prep_k<<<41, 256, 0, stream>>>(We1, a1, Wen1, Weu1, 0, Qt1, R1, U);
  prep_k<<<41, 256, 0, stream>>>(We2, a2, Wen2, Weu2, 1, Qt2, R2, U);
  se12_k<<<(E + 255)/256, 256, 0, stream>>>(ea, Qt1, Qt2, col, E, se1c, se2c, eac);

  const int gridNP   = (N + 63)/64;
  const int gridNode = (N + 7)/8;

  // ---- layer 1 ----
  node_prep<128><<<gridNP, 256, 0, stream>>>(x, Wn1, a1, Wen1, N, sdst, ssrc, xwb);
  aggfin_k<0><<<gridNode, 512, 0, stream>>>(rp, colsrc, sdst, ssrc, se1c, xwb, eac, R1, N, x1, nullptr);

  // ---- layer 2 (original edge_attr) ----
  node_prep<32><<<gridNP, 256, 0, stream>>>(x1, Wn2, a2, Wen2, N, sdst, ssrc, xwb);
  aggfin_k<1><<<gridNode, 512, 0, stream>>>(rp, colsrc, sdst, ssrc, se2c, xwb, eac, R2, N, nemb2, outN);

  node_u<<<(N*32 + 255)/256, 256, 0, stream>>>(nemb2, Weu2, N, nu1, nu2);
  edge_out<<<(E + 255)/256, 256, 0, stream>>>(col, colsrc, dstc, nu1, nu2, eac, U, E, outE);
}

// Round 15
// 667.868 us; speedup vs baseline: 1.2437x; 1.2437x over previous
//
#include <hip/hip_runtime.h>
#include <hip/hip_bf16.h>

__device__ __forceinline__ float lrelu(float x){ return x > 0.f ? x : 0.01f*x; }
__device__ __forceinline__ float eluf(float x){ return x > 0.f ? x : __expf(x) - 1.f; }

// bf16 pack/unpack (RNE)
__device__ __forceinline__ unsigned packbf2(float a, float b){
  unsigned ua = __float_as_uint(a); ua += 0x7FFF + ((ua >> 16) & 1);
  unsigned ub = __float_as_uint(b); ub += 0x7FFF + ((ub >> 16) & 1);
  return (ua >> 16) | (ub & 0xFFFF0000u);
}
__device__ __forceinline__ float bflo(unsigned u){ return __uint_as_float(u << 16); }
__device__ __forceinline__ float bfhi(unsigned u){ return __uint_as_float(u & 0xFFFF0000u); }

// ---------- edge_index dtype normalize ----------
__global__ void detect_idx(const int* __restrict__ p, int words, int* __restrict__ flag){
  __shared__ int any;
  if (threadIdx.x == 0) any = 0;
  __syncthreads();
  int v = 0;
  for (int i = threadIdx.x; i < words/2; i += blockDim.x) v |= p[2*i + 1];
  if (v) atomicOr(&any, 1);
  __syncthreads();
  if (threadIdx.x == 0) *flag = (any == 0) ? 1 : 0;
}

__global__ void convert_idx(const void* __restrict__ src, int n, const int* __restrict__ flag,
                            int* __restrict__ out){
  int i = blockIdx.x*256 + threadIdx.x;
  if (i >= n) return;
  out[i] = (*flag) ? (int)((const long long*)src)[i] : ((const int*)src)[i];
}

// ---------- CSR ----------
__global__ void hist_k(const int* __restrict__ dst, int E, int* __restrict__ deg){
  int e = blockIdx.x*256 + threadIdx.x;
  if (e < E) atomicAdd(&deg[dst[e]], 1);
}

__launch_bounds__(1024)
__global__ void scan_k(const int* __restrict__ deg, int N,
                       int* __restrict__ rp, int* __restrict__ cursor){
  __shared__ int part[1024];
  int tid = threadIdx.x;
  int chunk = (N + 1023) / 1024;
  int lo = tid*chunk, hi = min(lo + chunk, N);
  int s = 0;
  for (int i = lo; i < hi; i++) s += deg[i];
  part[tid] = s;
  __syncthreads();
  // Hillis-Steele inclusive scan over the 1024 partials
  for (int off = 1; off < 1024; off <<= 1){
    int t = (tid >= off) ? part[tid - off] : 0;
    __syncthreads();
    part[tid] += t;
    __syncthreads();
  }
  int run = part[tid] - s;          // exclusive prefix of this chunk
  if (tid == 1023) rp[N] = part[1023];
  for (int i = lo; i < hi; i++){
    rp[i] = run; cursor[i] = run;
    run += deg[i];
  }
}

// scatter: colsrc[p]=src[e], col[p]=e, dstc[p]=dst[e]
__global__ void scatter_k(const int* __restrict__ srcA, const int* __restrict__ dstA, int E,
                          int* __restrict__ cursor, int* __restrict__ colsrc,
                          int* __restrict__ col, int* __restrict__ dstc){
  int e = blockIdx.x*256 + threadIdx.x;
  if (e < E){
    int d = dstA[e];
    int p = atomicAdd(&cursor[d], 1);
    colsrc[p] = srcA[e];
    col[p] = e;
    dstc[p] = d;
  }
}

// ---------- folded weights (R: k-major, as staged into LDS by aggfin) ----------
__global__ void prep_k(const float* __restrict__ We, const float* __restrict__ a,
                       const float* __restrict__ Wen, const float* __restrict__ Weu,
                       int doU, float* __restrict__ Qt, float* __restrict__ R,
                       float* __restrict__ U){
  int idx = blockIdx.x*256 + threadIdx.x;
  if (idx < 256){
    int h = idx >> 6, k = idx & 63;
    float s = 0.f;
    for (int c = 0; c < 32; c++) s += We[k*128 + h*32 + c] * a[64 + c];
    Qt[h*64 + k] = s;
  } else if (idx < 256 + 8192){
    int t = idx - 256;
    int k = t >> 7, j = t & 127;      // j = h*32+d
    int h = j >> 5, d = j & 31;
    float s = 0.f;
    for (int c = 0; c < 32; c++) s += We[k*128 + h*32 + c] * Wen[(32 + c)*32 + d];
    R[k*128 + j] = s;
  } else if (doU && idx < 256 + 8192 + 2048){
    int t = idx - 256 - 8192;
    int k = t >> 5, d = t & 31;
    float s = 0.f;
    for (int c = 0; c < 32; c++){
      float mb = 0.25f*(We[k*128 + c] + We[k*128 + 32 + c] + We[k*128 + 64 + c] + We[k*128 + 96 + c]);
      s += mb * Weu[(64 + c)*32 + d];
    }
    U[k*32 + d] = s;
  }
}

// ---------- fused node-side: xp (LDS only) -> scores + xw(bf16 packed) ----------
template<int IN>
__launch_bounds__(256, 2)
__global__ void node_prep(const float* __restrict__ x, const float* __restrict__ Wn,
                          const float* __restrict__ a, const float* __restrict__ Wen,
                          int N, float* __restrict__ sdst, float* __restrict__ ssrc,
                          unsigned* __restrict__ xwb){
  __shared__ float sXpT[128][68];   // xp transposed [j][n]
  __shared__ float sX[32][68];      // x chunk transposed [k][n]
  __shared__ float sW[32][132];     // Wn chunk [k][j]
  __shared__ float sWen[32][36];    // Wen [c][d]
  __shared__ float sa[96];
  int tid = threadIdx.x;
  int nbase = blockIdx.x*64;

  if (tid < 96) sa[tid] = a[tid];
  {
    int c = tid >> 3, d4 = tid & 7;
    float4 v = *(const float4*)(Wen + c*32 + d4*4);
    *(float4*)&sWen[c][d4*4] = v;
  }

  int nq = tid >> 4, jq = tid & 15;   // thread = 4n x 8j
  float acc[8][4];
  #pragma unroll
  for (int ji = 0; ji < 8; ji++)
    #pragma unroll
    for (int ni = 0; ni < 4; ni++) acc[ji][ni] = 0.f;

  for (int kc = 0; kc < IN/32; kc++){
    __syncthreads();
    #pragma unroll
    for (int i = 0; i < 2; i++){
      int q = tid + i*256;
      int n = q >> 3, kq = q & 7;
      int nn = min(nbase + n, N - 1);
      float4 v = *(const float4*)(x + (size_t)nn*IN + kc*32 + kq*4);
      sX[kq*4 + 0][n] = v.x;
      sX[kq*4 + 1][n] = v.y;
      sX[kq*4 + 2][n] = v.z;
      sX[kq*4 + 3][n] = v.w;
    }
    #pragma unroll
    for (int i = 0; i < 4; i++){
      int q = tid + i*256;
      int kk = q >> 5, j4 = q & 31;
      float4 v = *(const float4*)(Wn + (size_t)(kc*32 + kk)*128 + j4*4);
      *(float4*)&sW[kk][j4*4] = v;
    }
    __syncthreads();
    #pragma unroll 8
    for (int k = 0; k < 32; k++){
      float4 xr = *(const float4*)&sX[k][nq*4];
      float4 w0 = *(const float4*)&sW[k][jq*8];
      float4 w1 = *(const float4*)&sW[k][jq*8 + 4];
      float xn[4] = {xr.x, xr.y, xr.z, xr.w};
      float wj[8] = {w0.x, w0.y, w0.z, w0.w, w1.x, w1.y, w1.z, w1.w};
      #pragma unroll
      for (int ji = 0; ji < 8; ji++)
        #pragma unroll
        for (int ni = 0; ni < 4; ni++)
          acc[ji][ni] += xn[ni] * wj[ji];
    }
  }
  #pragma unroll
  for (int ji = 0; ji < 8; ji++){
    float4 v = make_float4(acc[ji][0], acc[ji][1], acc[ji][2], acc[ji][3]);
    *(float4*)&sXpT[jq*8 + ji][nq*4] = v;
  }
  __syncthreads();

  // scores
  {
    int n = tid >> 2, h = tid & 3;
    float s1 = 0.f, s2 = 0.f;
    #pragma unroll
    for (int cc = 0; cc < 32; cc++){
      int c = (cc + tid) & 31;
      float v = sXpT[h*32 + c][n];
      s1 += v * sa[c];
      s2 += v * sa[32 + c];
    }
    int gn = nbase + n;
    if (gn < N){ sdst[gn*4 + h] = s1; ssrc[gn*4 + h] = s2; }
  }

  // xw packed bf16
  {
    int nd2 = tid >> 3, dq = tid & 7;
    int n0 = nd2*2, d0 = dq*4;
    float acc2[2][4][4];
    #pragma unroll
    for (int ni = 0; ni < 2; ni++)
      #pragma unroll
      for (int di = 0; di < 4; di++)
        #pragma unroll
        for (int h = 0; h < 4; h++) acc2[ni][di][h] = 0.f;
    #pragma unroll 4
    for (int c = 0; c < 32; c++){
      float4 wv = *(const float4*)&sWen[c][d0];
      float wvA[4] = {wv.x, wv.y, wv.z, wv.w};
      #pragma unroll
      for (int h = 0; h < 4; h++){
        float2 xv = *(const float2*)&sXpT[h*32 + c][n0];
        float xvA[2] = {xv.x, xv.y};
        #pragma unroll
        for (int ni = 0; ni < 2; ni++)
          #pragma unroll
          for (int di = 0; di < 4; di++)
            acc2[ni][di][h] += xvA[ni] * wvA[di];
      }
    }
    #pragma unroll
    for (int ni = 0; ni < 2; ni++){
      int gn = nbase + n0 + ni;
      if (gn < N){
        uint4 A, B;
        A.x = packbf2(acc2[ni][0][0], acc2[ni][0][1]);
        A.y = packbf2(acc2[ni][1][0], acc2[ni][1][1]);
        A.z = packbf2(acc2[ni][2][0], acc2[ni][2][1]);
        A.w = packbf2(acc2[ni][3][0], acc2[ni][3][1]);
        B.x = packbf2(acc2[ni][0][2], acc2[ni][0][3]);
        B.y = packbf2(acc2[ni][1][2], acc2[ni][1][3]);
        B.z = packbf2(acc2[ni][2][2], acc2[ni][2][3]);
        B.w = packbf2(acc2[ni][3][2], acc2[ni][3][3]);
        *(uint4*)(xwb + (size_t)gn*64 + d0) = A;
        *(uint4*)(xwb + (size_t)gn*64 + 32 + d0) = B;
      }
    }
  }
}

// ---------- edge pass, CSR-order GATHER (1 slot/thread, NO launch bound — the
// allocator's unbounded choice (VGPR 56) has proven optimal; bounds spill (R13)). ----------
__launch_bounds__(256)
__global__ void se12_k(const float* __restrict__ ea, const float* __restrict__ Qt1,
                       const float* __restrict__ Qt2, const int* __restrict__ col,
                       int E, float* __restrict__ se1c, float* __restrict__ se2c,
                       unsigned* __restrict__ eac){
  int p = blockIdx.x*256 + threadIdx.x;
  if (p >= E) return;
  int e = col[p];
  float x[64];
  {
    const float4* q = (const float4*)(ea + (size_t)e*64);
    #pragma unroll
    for (int t = 0; t < 16; t++){
      float4 v = q[t];
      x[4*t] = v.x; x[4*t+1] = v.y; x[4*t+2] = v.z; x[4*t+3] = v.w;
    }
  }
  float acc[8] = {0,0,0,0,0,0,0,0};
  #pragma unroll
  for (int t = 0; t < 16; t++){
    #pragma unroll
    for (int j = 0; j < 4; j++){
      const float* q1 = Qt1 + j*64 + 4*t;
      const float* q2 = Qt2 + j*64 + 4*t;
      acc[j]     += x[4*t]*q1[0] + x[4*t+1]*q1[1] + x[4*t+2]*q1[2] + x[4*t+3]*q1[3];
      acc[4 + j] += x[4*t]*q2[0] + x[4*t+1]*q2[1] + x[4*t+2]*q2[2] + x[4*t+3]*q2[3];
    }
  }
  *(float4*)(se1c + (size_t)p*4) = make_float4(acc[0], acc[1], acc[2], acc[3]);
  *(float4*)(se2c + (size_t)p*4) = make_float4(acc[4], acc[5], acc[6], acc[7]);
  unsigned* dst = eac + (size_t)p*32;
  #pragma unroll
  for (int t = 0; t < 8; t++){
    uint4 wv;
    wv.x = packbf2(x[4*t    ], x[32 + 4*t    ]);
    wv.y = packbf2(x[4*t + 1], x[32 + 4*t + 1]);
    wv.z = packbf2(x[4*t + 2], x[32 + 4*t + 2]);
    wv.w = packbf2(x[4*t + 3], x[32 + 4*t + 3]);
    ((uint4*)dst)[t] = wv;
  }
}

// ---------- fused aggregate + finalize: 512 threads = 8 waves = 8 nodes/block. ----------
template<int MODE>   // 0: outF = elu(emb);  1: outF = emb raw, outElu = elu(emb)
__global__ void __launch_bounds__(512)
aggfin_k(const int* __restrict__ rp, const int* __restrict__ colsrc,
         const float* __restrict__ sdst, const float* __restrict__ ssrc,
         const float* __restrict__ sec, const unsigned* __restrict__ xwb,
         const unsigned* __restrict__ eac, const float* __restrict__ R,
         int N, float* __restrict__ outF, float* __restrict__ outElu){
  __shared__ float sR[8192];
  __shared__ float sG[8][4][64];
  {
    const float4* r4 = (const float4*)R;
    float4* s4 = (float4*)sR;
    s4[threadIdx.x]       = r4[threadIdx.x];
    s4[threadIdx.x + 512] = r4[threadIdx.x + 512];
    s4[threadIdx.x + 1024] = r4[threadIdx.x + 1024];
    s4[threadIdx.x + 1536] = r4[threadIdx.x + 1536];
  }
  __syncthreads();

  int nb   = threadIdx.x >> 6;     // wave id = node slot (0..7)
  int lane = threadIdx.x & 63;
  int half = lane >> 5;
  int c    = lane & 31;
  int nid  = blockIdx.x*8 + nb;
  bool act = nid < N;
  int n = act ? nid : N - 1;
  float4 sdv = *(const float4*)(sdst + (size_t)n*4);
  float4 snv = *(const float4*)(ssrc + (size_t)n*4);
  float sd[4] = {sdv.x, sdv.y, sdv.z, sdv.w};
  float dn[4], ax[4], g0[4], g1[4];
  {
    float sn[4] = {snv.x, snv.y, snv.z, snv.w};
    unsigned wA = xwb[(size_t)n*64 + c], wB = xwb[(size_t)n*64 + 32 + c];
    float xwh[4] = {bflo(wA), bfhi(wA), bflo(wB), bfhi(wB)};
    #pragma unroll
    for (int h = 0; h < 4; h++){
      if (half == 0){                                    // self loop (ep = 0)
        float ex = __expf(lrelu(sd[h] + sn[h]));
        dn[h] = ex;
        ax[h] = ex * xwh[h];
      } else { dn[h] = 0.f; ax[h] = 0.f; }
      g0[h] = 0.f; g1[h] = 0.f;
    }
  }
  int beg = rp[n], end = rp[n+1];
  #pragma unroll 2
  for (int i = beg + half; i < end; i += 2){
    int s = colsrc[i];
    float4 sv = *(const float4*)(sec + (size_t)i*4);
    float4 sr = *(const float4*)(ssrc + (size_t)s*4);
    unsigned ep = eac[(size_t)i*32 + c];
    unsigned wA = xwb[(size_t)s*64 + c];
    unsigned wB = xwb[(size_t)s*64 + 32 + c];
    float e0 = bflo(ep), e1 = bfhi(ep);
    float ex0 = __expf(lrelu(sd[0] + sr.x + sv.x));
    float ex1 = __expf(lrelu(sd[1] + sr.y + sv.y));
    float ex2 = __expf(lrelu(sd[2] + sr.z + sv.z));
    float ex3 = __expf(lrelu(sd[3] + sr.w + sv.w));
    dn[0] += ex0; dn[1] += ex1; dn[2] += ex2; dn[3] += ex3;
    ax[0] += ex0*bflo(wA); ax[1] += ex1*bfhi(wA);
    ax[2] += ex2*bflo(wB); ax[3] += ex3*bfhi(wB);
    g0[0] += ex0*e0; g0[1] += ex1*e0; g0[2] += ex2*e0; g0[3] += ex3*e0;
    g1[0] += ex0*e1; g1[1] += ex1*e1; g1[2] += ex2*e1; g1[3] += ex3*e1;
  }
  #pragma unroll
  for (int h = 0; h < 4; h++){
    dn[h] += __shfl_xor(dn[h], 32);
    ax[h] += __shfl_xor(ax[h], 32);
    g0[h] += __shfl_xor(g0[h], 32);
    g1[h] += __shfl_xor(g1[h], 32);
  }
  if (half == 0){
    #pragma unroll
    for (int h = 0; h < 4; h++){
      sG[nb][h][c]      = g0[h];
      sG[nb][h][32 + c] = g1[h];
    }
  }
  // no __syncthreads: sG[nb] written+read by the SAME wave (lgkmcnt orders it)
  float val = 0.f;
  #pragma unroll
  for (int hh = 0; hh < 2; hh++){
    int h = half*2 + hh;
    float s = ax[h];
    const float* g = &sG[nb][h][0];
    #pragma unroll 16
    for (int k = 0; k < 64; k++) s += g[k] * sR[k*128 + h*32 + c];
    val += s / (dn[h] + 1e-16f);
  }
  val += __shfl_xor(val, 32);
  val *= 0.25f;
  if (act && half == 0){
    if (MODE == 0){
      outF[(size_t)n*32 + c] = eluf(val);
    } else {
      outF[(size_t)n*32 + c] = val;
      outElu[(size_t)n*32 + c] = eluf(val);
    }
  }
}

// ---------- edge update (layer 2) ----------
__launch_bounds__(256)
__global__ void node_u(const float* __restrict__ nemb, const float* __restrict__ Weu,
                       int N, float* __restrict__ nu1, float* __restrict__ nu2){
  __shared__ float w1[1024], w2[1024];
  for (int i = threadIdx.x; i < 1024; i += 256){ w1[i] = Weu[i]; w2[i] = Weu[1024 + i]; }
  __syncthreads();
  int idx = blockIdx.x*256 + threadIdx.x;
  if (idx >= N*32) return;
  int n = idx >> 5, d = idx & 31;
  float s1 = 0.f, s2 = 0.f;
  #pragma unroll
  for (int c = 0; c < 32; c++){
    float v = nemb[n*32 + c];
    s1 += v * w1[c*32 + d];
    s2 += v * w2[c*32 + d];
  }
  nu1[idx] = s1;
  nu2[idx] = s2;
}

// ---------- edge output, CSR-order: lane = CSR slot p; reads eac[p] (bf16, sequential),
// nu gathers; writes out[col[p]] — full 128B-line scatter (no amplification). ----------
__launch_bounds__(256)
__global__ void edge_out(const int* __restrict__ col, const int* __restrict__ colsrc,
                         const int* __restrict__ dstc,
                         const float* __restrict__ nu1, const float* __restrict__ nu2,
                         const unsigned* __restrict__ eac, const float* __restrict__ U,
                         int E, float* __restrict__ out){
  int p = blockIdx.x*256 + threadIdx.x;
  if (p >= E) return;
  int e = col[p], s = colsrc[p], d = dstc[p];
  unsigned w[32];
  {
    const uint4* q = (const uint4*)(eac + (size_t)p*32);
    #pragma unroll
    for (int t = 0; t < 8; t++){
      uint4 v = q[t];
      w[4*t] = v.x; w[4*t+1] = v.y; w[4*t+2] = v.z; w[4*t+3] = v.w;
    }
  }
  float acc[32];
  {
    const float4* a4 = (const float4*)(nu1 + (size_t)s*32);
    const float4* b4 = (const float4*)(nu2 + (size_t)d*32);
    #pragma unroll
    for (int t = 0; t < 8; t++){
      float4 av = a4[t], bv = b4[t];
      acc[4*t]     = av.x + bv.x;
      acc[4*t + 1] = av.y + bv.y;
      acc[4*t + 2] = av.z + bv.z;
      acc[4*t + 3] = av.w + bv.w;
    }
  }
  #pragma unroll 4
  for (int t = 0; t < 32; t++){
    float lo = bflo(w[t]);          // ea[t]
    float hi = bfhi(w[t]);          // ea[32+t]
    const float* u0 = U + (size_t)t*32;
    const float* u1 = U + (size_t)(32 + t)*32;
    #pragma unroll
    for (int j = 0; j < 32; j++)
      acc[j] += lo*u0[j] + hi*u1[j];
  }
  float4* o4 = (float4*)(out + (size_t)e*32);
  #pragma unroll
  for (int t = 0; t < 8; t++)
    o4[t] = make_float4(fmaxf(acc[4*t], 0.f), fmaxf(acc[4*t + 1], 0.f),
                        fmaxf(acc[4*t + 2], 0.f), fmaxf(acc[4*t + 3], 0.f));
}

extern "C" void kernel_launch(void* const* d_in, const int* in_sizes, int n_in,
                              void* d_out, int out_size, void* d_ws, size_t ws_size,
                              hipStream_t stream){
  const float* x    = (const float*)d_in[0];
  const float* ea   = (const float*)d_in[1];
  const void*  eidx = d_in[2];
  const float* Wn1  = (const float*)d_in[3];
  const float* We1  = (const float*)d_in[4];
  const float* a1   = (const float*)d_in[5];
  const float* Wen1 = (const float*)d_in[6];
  const float* Weu1 = (const float*)d_in[7];  (void)Weu1;
  const float* Wn2  = (const float*)d_in[8];
  const float* We2  = (const float*)d_in[9];
  const float* a2   = (const float*)d_in[10];
  const float* Wen2 = (const float*)d_in[11];
  const float* Weu2 = (const float*)d_in[12];
  const int N = in_sizes[0] / 128;
  const int E = in_sizes[1] / 64;

  char* w = (char*)d_ws;
  size_t off = 0;
  auto alloc = [&](size_t bytes) -> char* {
    char* p = w + off;
    off = (off + bytes + 255) & ~(size_t)255;
    return p;
  };
  int*      flag   = (int*)     alloc(256);
  int*      idx32  = (int*)     alloc((size_t)2*E*4);
  int*      deg    = (int*)     alloc((size_t)N*4);
  int*      cursor = (int*)     alloc((size_t)N*4);
  int*      rp     = (int*)     alloc(((size_t)N + 1)*4);
  int*      colsrc = (int*)     alloc((size_t)E*4);
  int*      col    = (int*)     alloc((size_t)E*4);
  int*      dstc   = (int*)     alloc((size_t)E*4);
  float*    sdst   = (float*)   alloc((size_t)N*4*4);
  float*    ssrc   = (float*)   alloc((size_t)N*4*4);
  unsigned* xwb    = (unsigned*)alloc((size_t)N*64*4);
  float*    se1c   = (float*)   alloc((size_t)E*4*4);
  float*    se2c   = (float*)   alloc((size_t)E*4*4);
  unsigned* eac    = (unsigned*)alloc((size_t)E*32*4);
  float*    x1     = (float*)   alloc((size_t)N*32*4);
  float*    nemb2  = (float*)   alloc((size_t)N*32*4);
  float*    nu1    = (float*)   alloc((size_t)N*32*4);
  float*    nu2    = (float*)   alloc((size_t)N*32*4);
  float*    Qt1    = (float*)   alloc(4*64*4);
  float*    Qt2    = (float*)   alloc(4*64*4);
  float*    R1     = (float*)   alloc(64*128*4);
  float*    R2     = (float*)   alloc(64*128*4);
  float*    U      = (float*)   alloc(64*32*4);

  float* outN = (float*)d_out;
  float* outE = outN + (size_t)N*32;

  const int* srcA = idx32;
  const int* dstA = idx32 + E;

  // graph normalize + CSR over dst
  detect_idx<<<1, 1024, 0, stream>>>((const int*)eidx, (2*E < 8192) ? 2*E : 8192, flag);
  convert_idx<<<(2*E + 255)/256, 256, 0, stream>>>(eidx, 2*E, flag, idx32);
  hipMemsetAsync(deg, 0, (size_t)N*4, stream);
  hist_k<<<(E + 255)/256, 256, 0, stream>>>(dstA, E, deg);
  scan_k<<<1, 1024, 0, stream>>>(deg, N, rp, cursor);
  scatter_k<<<(E + 255)/256, 256, 0, stream>>>(srcA, dstA, E, cursor, colsrc, col, dstc);

  // folded weights + edge pass (CSR-order gather; sequential writes)
  prep_k<<<41, 256, 0, stream>>>(We1, a1, Wen1, Weu1, 0, Qt1, R1, U);
  prep_k<<<41, 256, 0, stream>>>(We2, a2, Wen2, Weu2, 1, Qt2, R2, U);
  se12_k<<<(E + 255)/256, 256, 0, stream>>>(ea, Qt1, Qt2, col, E, se1c, se2c, eac);

  const int gridNP   = (N + 63)/64;
  const int gridNode = (N + 7)/8;

  // ---- layer 1 ----
  node_prep<128><<<gridNP, 256, 0, stream>>>(x, Wn1, a1, Wen1, N, sdst, ssrc, xwb);
  aggfin_k<0><<<gridNode, 512, 0, stream>>>(rp, colsrc, sdst, ssrc, se1c, xwb, eac, R1, N, x1, nullptr);

  // ---- layer 2 (original edge_attr) ----
  node_prep<32><<<gridNP, 256, 0, stream>>>(x1, Wn2, a2, Wen2, N, sdst, ssrc, xwb);
  aggfin_k<1><<<gridNode, 512, 0, stream>>>(rp, colsrc, sdst, ssrc, se2c, xwb, eac, R2, N, nemb2, outN);

  node_u<<<(N*32 + 255)/256, 256, 0, stream>>>(nemb2, Weu2, N, nu1, nu2);
  edge_out<<<(E + 255)/256, 256, 0, stream>>>(col, colsrc, dstc, nu1, nu2, eac, U, E, outE);
}